// Round 12
// baseline (188.744 us; speedup 1.0000x reference)
//
#include <hip/hip_runtime.h>

#define GROUPS 2
#define NUM_VARS 320
#define NVT 640
#define DIM 512
#define VAR_DIM 128
#define NTOK 48000
#define TM 32            // (fallback path) tokens per block
#define TMF 64           // fast-path tokens per block (4 row-tiles)
#define BLOCK 256
#define KCH 256          // (fallback path) K-chunk staged in LDS
#define XP 264           // (fallback path) padded row stride (ushorts)
#define NT16 40          // total 16-var tiles (NVT/16)
#define NKS 16           // total 32-k slices (DIM/32)
#define NTILE (NTOK / 16)   // 3000 16-token tiles
#define TSTRIDE (NKS * 2 * 512)   // u16 elements per packed 16-token tile

typedef short bf16x8 __attribute__((ext_vector_type(8)));
typedef float f32x4  __attribute__((ext_vector_type(4)));
typedef unsigned short u16;
typedef u16 u16x4 __attribute__((ext_vector_type(4)));
typedef u16 u16x8 __attribute__((ext_vector_type(8)));

__device__ inline u16 bf16_rne(float f) {
    unsigned u = __builtin_bit_cast(unsigned, f);
    return (u16)((u + 0x7fffu + ((u >> 16) & 1u)) >> 16);
}
__device__ inline void split2(float f, u16& h, u16& l) {
    h = bf16_rne(f);
    float fh = __builtin_bit_cast(float, (unsigned)h << 16);
    l = bf16_rne(f - fh);
}

// async global->LDS, 16B per lane: LDS dest = uniform base + lane*16 (HW),
// global src = per-lane address. Packed-fragment tiles are linear in lane
// order, so this is a drop-in (guide §5 / m97).
__device__ __forceinline__ void gll16(const void* g, void* l) {
    __builtin_amdgcn_global_load_lds(
        (const __attribute__((address_space(1))) unsigned int*)g,
        (__attribute__((address_space(3))) unsigned int*)l,
        16, 0, 0);
}

// Pre-split W into bf16 hi/lo in MFMA-fragment order (validated R5-R11, absmax=0):
//   offset = ((v16*NKS+ks)*2+hilo)*512 + lane*8 + j
//   row = v16*16 + (lane&15), k = ks*32 + 8*(lane>>4) + j.
__global__ void pack_w_kernel(const float* __restrict__ W, u16* __restrict__ Wpk) {
    int idx = blockIdx.x * blockDim.x + threadIdx.x;
    if (idx >= NT16 * NKS * 64 * 8) return;
    int j    = idx & 7;
    int lane = (idx >> 3) & 63;
    int ks   = (idx >> 9) & 15;
    int v16  = idx >> 13;
    int row  = v16 * 16 + (lane & 15);
    int k    = ks * 32 + 8 * (lane >> 4) + j;
    u16 h, l;
    split2(W[(size_t)row * DIM + k], h, l);
    size_t base = (size_t)((v16 * NKS + ks) * 2) * 512 + lane * 8 + j;
    Wpk[base]       = h;
    Wpk[base + 512] = l;
}

// Pre-split x into bf16 hi/lo in MFMA A-fragment order (validated R8-R11, absmax=0):
//   xpk[tile][ks][hilo][512], token = tile*16 + (lane&15), k = ks*32+8*(lane>>4)+j
__global__ void split_x_pack_kernel(const float* __restrict__ x,
                                    u16* __restrict__ xpk) {
    const int gw   = (blockIdx.x * blockDim.x + threadIdx.x) >> 6;  // wave = tile
    const int lane = threadIdx.x & 63;
    if (gw >= NTILE) return;
    const int l15 = lane & 15, l4 = lane >> 4;
    const float* xr = x + (size_t)(gw * 16 + l15) * DIM + 8 * l4;
    u16* dst = xpk + (size_t)gw * TSTRIDE + lane * 8;
#pragma unroll 4
    for (int ks = 0; ks < NKS; ++ks) {
        float4 a = *(const float4*)(xr + ks * 32);
        float4 b = *(const float4*)(xr + ks * 32 + 4);
        u16x8 hv, lv; u16 h, l;
        split2(a.x, h, l); hv[0] = h; lv[0] = l;
        split2(a.y, h, l); hv[1] = h; lv[1] = l;
        split2(a.z, h, l); hv[2] = h; lv[2] = l;
        split2(a.w, h, l); hv[3] = h; lv[3] = l;
        split2(b.x, h, l); hv[4] = h; lv[4] = l;
        split2(b.y, h, l); hv[5] = h; lv[5] = l;
        split2(b.z, h, l); hv[6] = h; lv[6] = l;
        split2(b.w, h, l); hv[7] = h; lv[7] = l;
        *(u16x8*)(dst + ks * 1024)       = hv;
        *(u16x8*)(dst + ks * 1024 + 512) = lv;
    }
}

// ---------- fast path: TMF=64 + 4-buffer LDS A-pipeline (3 ks ahead) --------
// R11 post-mortem: 2-ks-ahead staging gives only ~1 iteration of flight time;
// xpk staging is HBM/L3 latency (~400-900cy) so every ks convoys on the
// staging wait at the barrier. 4 buffers / 3-ahead -> ~3 iterations of budget,
// register-free (regs stay 80V+80A = 160/wave = 3 waves/SIMD; R10 cliff at
// >170). Steady-state wait is vmcnt(4): the 4 newest staging ops (ks+2, ks+3)
// may fly; staging(ks+1) + this iter's B loads must have landed.
__global__ __launch_bounds__(BLOCK, 2)
void vq_mfma_reg_kernel(const float* __restrict__ x,
                        const float* __restrict__ W,
                        const u16* __restrict__ xpk,
                        const u16* __restrict__ Wpk,
                        const float* __restrict__ bias,
                        const float* __restrict__ codebook,
                        float* __restrict__ out,
                        float* __restrict__ avg_out) {
    __shared__ u16 As[4][4][2][512];     // 4 bufs x 4 rt x (hi,lo) x 1KB = 32KB
    __shared__ float avg_s[NUM_VARS];
    __shared__ float tv_s[TMF][4][2];
    __shared__ int   ti_s[TMF][4][2];
    __shared__ float m_s[TMF], gap_s[TMF], sum_s[TMF];
    __shared__ int   i1_s[TMF], i2_s[TMF], kb_s[TMF];

    const int tid  = threadIdx.x;
    const int lane = tid & 63;
    const int ty   = tid >> 6;
    const int l15  = lane & 15;
    const int l4   = lane >> 4;
    const int g    = blockIdx.x & 1;
    const int n0   = (blockIdx.x >> 1) * TMF;

    for (int i = tid; i < NUM_VARS; i += BLOCK) avg_s[i] = 0.f;

    const f32x4 zf = {0.f, 0.f, 0.f, 0.f};
    f32x4 acc[4][5];
#pragma unroll
    for (int rt = 0; rt < 4; ++rt)
#pragma unroll
        for (int ct = 0; ct < 5; ++ct) acc[rt][ct] = zf;

    // wave ty stages rt==ty's tile; all waves consume all rt from LDS
    const u16* xa_st = xpk + (size_t)((blockIdx.x >> 1) * 4 + ty) * TSTRIDE + lane * 8;
    const u16* wpk_b = Wpk + (size_t)(g * 20 + ty * 5) * TSTRIDE + lane * 8;

    // prologue: stage ks=0,1,2 -> buf 0,1,2
    gll16(xa_st,        &As[0][ty][0][0]);
    gll16(xa_st + 512,  &As[0][ty][1][0]);
    gll16(xa_st + 1024, &As[1][ty][0][0]);
    gll16(xa_st + 1536, &As[1][ty][1][0]);
    gll16(xa_st + 2048, &As[2][ty][0][0]);
    gll16(xa_st + 2560, &As[2][ty][1][0]);
    asm volatile("s_waitcnt vmcnt(4)" ::: "memory");   // ks0 pair landed
    __builtin_amdgcn_s_barrier();

#pragma unroll 1
    for (int ks = 0; ks < NKS; ++ks) {
        const int cur = ks & 3;
        // B fragments (L2-resident); compiler pipelines these under the MFMAs
        bf16x8 bh[5], bl[5];
#pragma unroll
        for (int ct = 0; ct < 5; ++ct) {
            const u16* wp = wpk_b + (size_t)(ct * NKS + ks) * 1024;
            bh[ct] = *(const bf16x8*)wp;
            bl[ct] = *(const bf16x8*)(wp + 512);
        }
        // per-rt: ds_read A (8 VGPR live) then 15 MFMAs
#pragma unroll
        for (int rt = 0; rt < 4; ++rt) {
            bf16x8 ah = *(const bf16x8*)&As[cur][rt][0][lane * 8];
            bf16x8 al = *(const bf16x8*)&As[cur][rt][1][lane * 8];
#pragma unroll
            for (int ct = 0; ct < 5; ++ct) {
                acc[rt][ct] = __builtin_amdgcn_mfma_f32_16x16x32_bf16(ah, bh[ct], acc[rt][ct], 0, 0, 0);
                acc[rt][ct] = __builtin_amdgcn_mfma_f32_16x16x32_bf16(ah, bl[ct], acc[rt][ct], 0, 0, 0);
                acc[rt][ct] = __builtin_amdgcn_mfma_f32_16x16x32_bf16(al, bh[ct], acc[rt][ct], 0, 0, 0);
            }
        }
        // stage ks+3 into buf (ks+3)&3 (that buffer was read at iter ks-1;
        // every wave passed that barrier with lgkmcnt(0) -> safe to overwrite)
        if (ks + 3 < NKS) {
            const int nb = (ks + 3) & 3;
            gll16(xa_st + (size_t)(ks + 3) * 1024,       &As[nb][ty][0][0]);
            gll16(xa_st + (size_t)(ks + 3) * 1024 + 512, &As[nb][ty][1][0]);
        }
        // need staging(ks+1) landed; staging(ks+2),(ks+3) = 4 ops may fly.
        if (ks < NKS - 3) {
            asm volatile("s_waitcnt vmcnt(4) lgkmcnt(0)" ::: "memory");
        } else if (ks == NKS - 3) {
            asm volatile("s_waitcnt vmcnt(2) lgkmcnt(0)" ::: "memory");
        } else {
            asm volatile("s_waitcnt vmcnt(0) lgkmcnt(0)" ::: "memory");
        }
        __builtin_amdgcn_s_barrier();
    }

    // bias (zeros in harness; kept for generality)
#pragma unroll
    for (int ct = 0; ct < 5; ++ct) {
        float bv = bias[g * NUM_VARS + ty * 80 + ct * 16 + l15];
#pragma unroll
        for (int rt = 0; rt < 4; ++rt)
#pragma unroll
            for (int j = 0; j < 4; ++j) acc[rt][ct][j] += bv;
    }

    // per-token wave-local top-2 (16-lane butterfly)
#pragma unroll
    for (int rt = 0; rt < 4; ++rt)
#pragma unroll
    for (int j = 0; j < 4; ++j) {
        float v1 = -3.4e38f, v2 = -3.4e38f;
        int   i1 = 0x7fffffff, i2 = 0x7fffffff;
#pragma unroll
        for (int ct = 0; ct < 5; ++ct) {
            float val = acc[rt][ct][j];
            int   vi  = ty * 80 + ct * 16 + l15;
            if ((val > v1) || (val == v1 && vi < i1)) { v2 = v1; i2 = i1; v1 = val; i1 = vi; }
            else if ((val > v2) || (val == v2 && vi < i2)) { v2 = val; i2 = vi; }
        }
#pragma unroll
        for (int off = 1; off <= 8; off <<= 1) {
            float o1 = __shfl_xor(v1, off); int oi1 = __shfl_xor(i1, off);
            float o2 = __shfl_xor(v2, off); int oi2 = __shfl_xor(i2, off);
            if ((o1 > v1) || (o1 == v1 && oi1 < i1)) { v2 = v1; i2 = i1; v1 = o1; i1 = oi1; }
            else if ((o1 > v2) || (o1 == v2 && oi1 < i2)) { v2 = o1; i2 = oi1; }
            if ((o2 > v1) || (o2 == v1 && oi2 < i1)) { v2 = v1; i2 = i1; v1 = o2; i1 = oi2; }
            else if ((o2 > v2) || (o2 == v2 && oi2 < i2)) { v2 = o2; i2 = oi2; }
        }
        if (l15 == 0) {
            const int T = rt * 16 + l4 * 4 + j;
            tv_s[T][ty][0] = v1; tv_s[T][ty][1] = v2;
            ti_s[T][ty][0] = i1; ti_s[T][ty][1] = i2;
        }
    }
    __syncthreads();

    // cross-wave merge (one thread per token)
    if (tid < TMF) {
        float v1 = -3.4e38f, v2 = -3.4e38f;
        int   i1 = 0x7fffffff, i2 = 0x7fffffff;
#pragma unroll
        for (int w = 0; w < 4; ++w)
#pragma unroll
            for (int q = 0; q < 2; ++q) {
                float val = tv_s[tid][w][q]; int vi = ti_s[tid][w][q];
                if ((val > v1) || (val == v1 && vi < i1)) { v2 = v1; i2 = i1; v1 = val; i1 = vi; }
                else if ((val > v2) || (val == v2 && vi < i2)) { v2 = val; i2 = vi; }
            }
        m_s[tid] = v1; gap_s[tid] = v1 - v2;
        i1_s[tid] = i1; i2_s[tid] = i2; kb_s[tid] = i1; sum_s[tid] = 0.f;
    }
    __syncthreads();

    // softmax: exp + per-token sum
#pragma unroll
    for (int rt = 0; rt < 4; ++rt)
#pragma unroll
    for (int j = 0; j < 4; ++j) {
        const int T = rt * 16 + l4 * 4 + j;
        const float m = m_s[T];
        float s = 0.f;
#pragma unroll
        for (int ct = 0; ct < 5; ++ct) {
            float e = __expf(acc[rt][ct][j] - m);
            acc[rt][ct][j] = e;
            s += e;
        }
#pragma unroll
        for (int off = 1; off <= 8; off <<= 1) s += __shfl_xor(s, off);
        if (l15 == 0) atomicAdd(&sum_s[T], s);
    }
    __syncthreads();

    // avg_probs partials: hoisted reciprocal, l4-shuffle reduce,
    // per-wave-exclusive plain adds
#pragma unroll
    for (int ct = 0; ct < 5; ++ct) {
        float tot = 0.f;
#pragma unroll
        for (int rt = 0; rt < 4; ++rt)
#pragma unroll
        for (int j = 0; j < 4; ++j) {
            const int T = rt * 16 + l4 * 4 + j;
            float v = acc[rt][ct][j] * (1.f / sum_s[T]);
            v += __shfl_xor(v, 16);
            v += __shfl_xor(v, 32);
            tot += v;
        }
        if (l4 == 0) avg_s[ty * 80 + ct * 16 + l15] += tot;
    }

    // f64 re-verify close argmaxes (bf16x3 logit err ~3e-4 << 0.05 gap)
    for (int t16 = 0; t16 < 16; ++t16) {
        const int T = ty * 16 + t16;
        if (gap_s[T] <= 0.05f) {
            const int i1 = i1_s[T], i2 = i2_s[T];
            const float* xr = x + (size_t)(n0 + T) * DIM;
            const float* w1 = W + (size_t)(g * NUM_VARS + i1) * DIM;
            const float* w2 = W + (size_t)(g * NUM_VARS + i2) * DIM;
            double d1 = 0.0, d2 = 0.0;
            for (int k = lane; k < DIM; k += 64) {
                double xv = (double)xr[k];
                d1 += xv * (double)w1[k];
                d2 += xv * (double)w2[k];
            }
#pragma unroll
            for (int off = 1; off <= 32; off <<= 1) {
                d1 += __shfl_xor(d1, off);
                d2 += __shfl_xor(d2, off);
            }
            d1 += (double)bias[g * NUM_VARS + i1];
            d2 += (double)bias[g * NUM_VARS + i2];
            if (lane == 0)
                kb_s[T] = (d2 > d1 || (d2 == d1 && i2 < i1)) ? i2 : i1;
        }
    }
    __syncthreads();

    // codebook gather -> out (coalesced float4): 64 tokens x 32 float4
#pragma unroll
    for (int i = 0; i < 8; ++i) {
        const int f = tid + i * BLOCK;
        const int T = f >> 5, p = f & 31;
        const int kb = kb_s[T];
        float4 cv = *(const float4*)(codebook +
                     (size_t)(g * NUM_VARS + kb) * VAR_DIM + p * 4);
        *(float4*)(out + (size_t)(n0 + T) * (GROUPS * VAR_DIM) + g * VAR_DIM + p * 4) = cv;
    }

    const float scale = 1.f / (float)NTOK;
    for (int i = tid; i < NUM_VARS; i += BLOCK)
        atomicAdd(&avg_out[g * NUM_VARS + i], avg_s[i] * scale);
}

// ---------------- fallback path (R6, proven): LDS-staged x ----------------
template <bool USE_WQ>
__global__ __launch_bounds__(BLOCK, 2)
void vq_mfma_kernel(const float* __restrict__ x,
                    const float* __restrict__ W,
                    const u16* __restrict__ Wpk,
                    const float* __restrict__ bias,
                    const float* __restrict__ codebook,
                    float* __restrict__ out,
                    float* __restrict__ avg_out) {
    __shared__ u16 xs_hi[TM][XP];
    __shared__ u16 xs_lo[TM][XP];
    __shared__ float avg_s[NUM_VARS];
    __shared__ float tv_s[TM][4][2];
    __shared__ int   ti_s[TM][4][2];
    __shared__ float m_s[TM], gap_s[TM], sum_s[TM];
    __shared__ int   i1_s[TM], i2_s[TM], kb_s[TM];

    const int tid  = threadIdx.x;
    const int lane = tid & 63;
    const int ty   = tid >> 6;
    const int l15  = lane & 15;
    const int l4   = lane >> 4;
    const int g    = blockIdx.x & 1;
    const int n0   = (blockIdx.x >> 1) * TM;

    for (int i = tid; i < NUM_VARS; i += BLOCK) avg_s[i] = 0.f;

    const f32x4 zf = {0.f, 0.f, 0.f, 0.f};
    f32x4 acc[2][5];
#pragma unroll
    for (int rt = 0; rt < 2; ++rt)
#pragma unroll
        for (int ct = 0; ct < 5; ++ct) acc[rt][ct] = zf;

    const int vw = g * NUM_VARS + ty * 80;

    for (int c = 0; c < DIM / KCH; ++c) {
        __syncthreads();
        {
            const int t  = tid >> 3;
            const int kb = (tid & 7) * 4;
            const float* xp = x + (size_t)(n0 + t) * DIM + c * KCH;
#pragma unroll
            for (int i = 0; i < 8; ++i) {
                const int k = kb + i * 32;
                float4 v = *(const float4*)(xp + k);
                u16x4 hv, lv; u16 h, l;
                split2(v.x, h, l); hv[0] = h; lv[0] = l;
                split2(v.y, h, l); hv[1] = h; lv[1] = l;
                split2(v.z, h, l); hv[2] = h; lv[2] = l;
                split2(v.w, h, l); hv[3] = h; lv[3] = l;
                *(u16x4*)&xs_hi[t][k] = hv;
                *(u16x4*)&xs_lo[t][k] = lv;
            }
        }
        __syncthreads();
#pragma unroll
        for (int ks = 0; ks < KCH / 32; ++ks) {
            const int ko = ks * 32 + 8 * l4;
            bf16x8 ah0 = *(const bf16x8*)&xs_hi[l15][ko];
            bf16x8 al0 = *(const bf16x8*)&xs_lo[l15][ko];
            bf16x8 ah1 = *(const bf16x8*)&xs_hi[16 + l15][ko];
            bf16x8 al1 = *(const bf16x8*)&xs_lo[16 + l15][ko];
            const int ksg = c * (KCH / 32) + ks;
#pragma unroll
            for (int ct = 0; ct < 5; ++ct) {
                bf16x8 bh, bl;
                if (USE_WQ) {
                    const int v16g = g * (NUM_VARS / 16) + ty * 5 + ct;
                    const u16* wp = Wpk + (size_t)((v16g * NKS + ksg) * 2) * 512 + lane * 8;
                    bh = *(const bf16x8*)wp;
                    bl = *(const bf16x8*)(wp + 512);
                } else {
                    const int kg = ksg * 32 + 8 * l4;
                    const float* wp = W + (size_t)(vw + ct * 16 + l15) * DIM + kg;
                    float4 wa = *(const float4*)wp;
                    float4 wb = *(const float4*)(wp + 4);
                    u16 h, l;
                    split2(wa.x, h, l); bh[0] = (short)h; bl[0] = (short)l;
                    split2(wa.y, h, l); bh[1] = (short)h; bl[1] = (short)l;
                    split2(wa.z, h, l); bh[2] = (short)h; bl[2] = (short)l;
                    split2(wa.w, h, l); bh[3] = (short)h; bl[3] = (short)l;
                    split2(wb.x, h, l); bh[4] = (short)h; bl[4] = (short)l;
                    split2(wb.y, h, l); bh[5] = (short)h; bl[5] = (short)l;
                    split2(wb.z, h, l); bh[6] = (short)h; bl[6] = (short)l;
                    split2(wb.w, h, l); bh[7] = (short)h; bl[7] = (short)l;
                }
                acc[0][ct] = __builtin_amdgcn_mfma_f32_16x16x32_bf16(ah0, bh, acc[0][ct], 0, 0, 0);
                acc[0][ct] = __builtin_amdgcn_mfma_f32_16x16x32_bf16(ah0, bl, acc[0][ct], 0, 0, 0);
                acc[0][ct] = __builtin_amdgcn_mfma_f32_16x16x32_bf16(al0, bh, acc[0][ct], 0, 0, 0);
                acc[1][ct] = __builtin_amdgcn_mfma_f32_16x16x32_bf16(ah1, bh, acc[1][ct], 0, 0, 0);
                acc[1][ct] = __builtin_amdgcn_mfma_f32_16x16x32_bf16(ah1, bl, acc[1][ct], 0, 0, 0);
                acc[1][ct] = __builtin_amdgcn_mfma_f32_16x16x32_bf16(al1, bh, acc[1][ct], 0, 0, 0);
            }
        }
    }

#pragma unroll
    for (int ct = 0; ct < 5; ++ct) {
        float bv = bias[vw + ct * 16 + l15];
#pragma unroll
        for (int rt = 0; rt < 2; ++rt)
#pragma unroll
            for (int j = 0; j < 4; ++j) acc[rt][ct][j] += bv;
    }

#pragma unroll
    for (int rt = 0; rt < 2; ++rt)
#pragma unroll
    for (int j = 0; j < 4; ++j) {
        float v1 = -3.4e38f, v2 = -3.4e38f;
        int   i1 = 0x7fffffff, i2 = 0x7fffffff;
#pragma unroll
        for (int ct = 0; ct < 5; ++ct) {
            float val = acc[rt][ct][j];
            int   vi  = ty * 80 + ct * 16 + l15;
            if ((val > v1) || (val == v1 && vi < i1)) { v2 = v1; i2 = i1; v1 = val; i1 = vi; }
            else if ((val > v2) || (val == v2 && vi < i2)) { v2 = val; i2 = vi; }
        }
#pragma unroll
        for (int off = 1; off <= 8; off <<= 1) {
            float o1 = __shfl_xor(v1, off); int oi1 = __shfl_xor(i1, off);
            float o2 = __shfl_xor(v2, off); int oi2 = __shfl_xor(i2, off);
            if ((o1 > v1) || (o1 == v1 && oi1 < i1)) { v2 = v1; i2 = i1; v1 = o1; i1 = oi1; }
            else if ((o1 > v2) || (o1 == v2 && oi1 < i2)) { v2 = o1; i2 = oi1; }
            if ((o2 > v1) || (o2 == v1 && oi2 < i1)) { v2 = v1; i2 = i1; v1 = o2; i1 = oi2; }
            else if ((o2 > v2) || (o2 == v2 && oi2 < i2)) { v2 = o2; i2 = oi2; }
        }
        if (l15 == 0) {
            const int T = rt * 16 + l4 * 4 + j;
            tv_s[T][ty][0] = v1; tv_s[T][ty][1] = v2;
            ti_s[T][ty][0] = i1; ti_s[T][ty][1] = i2;
        }
    }
    __syncthreads();

    if (tid < TM) {
        float v1 = -3.4e38f, v2 = -3.4e38f;
        int   i1 = 0x7fffffff, i2 = 0x7fffffff;
#pragma unroll
        for (int w = 0; w < 4; ++w)
#pragma unroll
            for (int q = 0; q < 2; ++q) {
                float val = tv_s[tid][w][q]; int vi = ti_s[tid][w][q];
                if ((val > v1) || (val == v1 && vi < i1)) { v2 = v1; i2 = i1; v1 = val; i1 = vi; }
                else if ((val > v2) || (val == v2 && vi < i2)) { v2 = val; i2 = vi; }
            }
        m_s[tid] = v1; gap_s[tid] = v1 - v2;
        i1_s[tid] = i1; i2_s[tid] = i2; kb_s[tid] = i1; sum_s[tid] = 0.f;
    }
    __syncthreads();

#pragma unroll
    for (int rt = 0; rt < 2; ++rt)
#pragma unroll
    for (int j = 0; j < 4; ++j) {
        const int T = rt * 16 + l4 * 4 + j;
        const float m = m_s[T];
        float s = 0.f;
#pragma unroll
        for (int ct = 0; ct < 5; ++ct) {
            float e = expf(acc[rt][ct][j] - m);
            acc[rt][ct][j] = e;
            s += e;
        }
#pragma unroll
        for (int off = 1; off <= 8; off <<= 1) s += __shfl_xor(s, off);
        if (l15 == 0) atomicAdd(&sum_s[T], s);
    }
    __syncthreads();

#pragma unroll
    for (int ct = 0; ct < 5; ++ct) {
        float tot = 0.f;
#pragma unroll
        for (int rt = 0; rt < 2; ++rt)
#pragma unroll
        for (int j = 0; j < 4; ++j) {
            const int T = rt * 16 + l4 * 4 + j;
            float v = acc[rt][ct][j] / sum_s[T];
            v += __shfl_xor(v, 16);
            v += __shfl_xor(v, 32);
            tot += v;
        }
        if (l4 == 0) avg_s[ty * 80 + ct * 16 + l15] += tot;
    }

    for (int t8 = 0; t8 < 8; ++t8) {
        const int T = ty * 8 + t8;
        if (gap_s[T] <= 0.05f) {
            const int i1 = i1_s[T], i2 = i2_s[T];
            const float* xr = x + (size_t)(n0 + T) * DIM;
            const float* w1 = W + (size_t)(g * NUM_VARS + i1) * DIM;
            const float* w2 = W + (size_t)(g * NUM_VARS + i2) * DIM;
            double d1 = 0.0, d2 = 0.0;
            for (int k = lane; k < DIM; k += 64) {
                double xv = (double)xr[k];
                d1 += xv * (double)w1[k];
                d2 += xv * (double)w2[k];
            }
#pragma unroll
            for (int off = 1; off <= 32; off <<= 1) {
                d1 += __shfl_xor(d1, off);
                d2 += __shfl_xor(d2, off);
            }
            d1 += (double)bias[g * NUM_VARS + i1];
            d2 += (double)bias[g * NUM_VARS + i2];
            if (lane == 0)
                kb_s[T] = (d2 > d1 || (d2 == d1 && i2 < i1)) ? i2 : i1;
        }
    }
    __syncthreads();

#pragma unroll
    for (int i = 0; i < 4; ++i) {
        const int f = tid + i * BLOCK;
        const int T = f >> 5, p = f & 31;
        const int kb = kb_s[T];
        float4 cv = *(const float4*)(codebook +
                     (size_t)(g * NUM_VARS + kb) * VAR_DIM + p * 4);
        *(float4*)(out + (size_t)(n0 + T) * (GROUPS * VAR_DIM) + g * VAR_DIM + p * 4) = cv;
    }

    const float scale = 1.f / (float)NTOK;
    for (int i = tid; i < NUM_VARS; i += BLOCK)
        atomicAdd(&avg_out[g * NUM_VARS + i], avg_s[i] * scale);
}

extern "C" void kernel_launch(void* const* d_in, const int* in_sizes, int n_in,
                              void* d_out, int out_size, void* d_ws, size_t ws_size,
                              hipStream_t stream) {
    const float* x  = (const float*)d_in[0];
    const float* W  = (const float*)d_in[1];
    const float* b  = (const float*)d_in[2];
    const float* cb = (const float*)d_in[3];
    float* out = (float*)d_out;
    float* avg = out + (size_t)NTOK * GROUPS * VAR_DIM;

    hipMemsetAsync(avg, 0, NVT * sizeof(float), stream);

    const size_t wpk_bytes = (size_t)NT16 * NKS * 2 * 512 * sizeof(u16);        // 1.31 MB
    const size_t xpk_bytes = (size_t)NTILE * NKS * 2 * 512 * sizeof(u16);       // 98.3 MB
    const size_t full_bytes = wpk_bytes + xpk_bytes;                            // 99.7 MB

    if (ws_size >= full_bytes) {
        u16* Wpk = (u16*)d_ws;
        u16* xpk = (u16*)((char*)d_ws + wpk_bytes);
        pack_w_kernel<<<(NT16 * NKS * 64 * 8 + 255) / 256, 256, 0, stream>>>(W, Wpk);
        split_x_pack_kernel<<<(NTILE + 3) / 4, 256, 0, stream>>>(x, xpk);
        vq_mfma_reg_kernel<<<(NTOK / TMF) * GROUPS, BLOCK, 0, stream>>>(
            x, W, xpk, Wpk, b, cb, out, avg);
    } else if (ws_size >= wpk_bytes) {
        u16* Wpk = (u16*)d_ws;
        pack_w_kernel<<<(NT16 * NKS * 64 * 8 + 255) / 256, 256, 0, stream>>>(W, Wpk);
        vq_mfma_kernel<true><<<(NTOK / TM) * GROUPS, BLOCK, 0, stream>>>(x, W, Wpk, b, cb, out, avg);
    } else {
        vq_mfma_kernel<false><<<(NTOK / TM) * GROUPS, BLOCK, 0, stream>>>(x, W, nullptr, b, cb, out, avg);
    }
}

// Round 13
// 164.546 us; speedup vs baseline: 1.1471x; 1.1471x over previous
//
#include <hip/hip_runtime.h>

#define GROUPS 2
#define NUM_VARS 320
#define NVT 640
#define DIM 512
#define VAR_DIM 128
#define NTOK 48000
#define TM 32            // (fallback path) tokens per block
#define TMF 64           // fast-path tokens per block (4 row-tiles)
#define BLOCK 256
#define KCH 256          // (fallback path) K-chunk staged in LDS
#define XP 264           // (fallback path) padded row stride (ushorts)
#define NT16 40          // total 16-var tiles (NVT/16)
#define NKS 16           // total 32-k slices (DIM/32)
#define TSTRIDE (NKS * 2 * 512)   // u16 elements per packed W 16-row tile

typedef short bf16x8 __attribute__((ext_vector_type(8)));
typedef float f32x4  __attribute__((ext_vector_type(4)));
typedef unsigned short u16;
typedef u16 u16x4 __attribute__((ext_vector_type(4)));
typedef u16 u16x8 __attribute__((ext_vector_type(8)));

__device__ inline u16 bf16_rne(float f) {
    unsigned u = __builtin_bit_cast(unsigned, f);
    return (u16)((u + 0x7fffu + ((u >> 16) & 1u)) >> 16);
}
__device__ inline void split2(float f, u16& h, u16& l) {
    h = bf16_rne(f);
    float fh = __builtin_bit_cast(float, (unsigned)h << 16);
    l = bf16_rne(f - fh);
}
__device__ inline void split8(float4 a, float4 b, u16x8& hv, u16x8& lv) {
    u16 h, l;
    split2(a.x, h, l); hv[0] = h; lv[0] = l;
    split2(a.y, h, l); hv[1] = h; lv[1] = l;
    split2(a.z, h, l); hv[2] = h; lv[2] = l;
    split2(a.w, h, l); hv[3] = h; lv[3] = l;
    split2(b.x, h, l); hv[4] = h; lv[4] = l;
    split2(b.y, h, l); hv[5] = h; lv[5] = l;
    split2(b.z, h, l); hv[6] = h; lv[6] = l;
    split2(b.w, h, l); hv[7] = h; lv[7] = l;
}

// Pre-split W into bf16 hi/lo in MFMA-fragment order (validated R5-R12, absmax=0):
//   offset = ((v16*NKS+ks)*2+hilo)*512 + lane*8 + j
//   row = v16*16 + (lane&15), k = ks*32 + 8*(lane>>4) + j.
__global__ void pack_w_kernel(const float* __restrict__ W, u16* __restrict__ Wpk) {
    int idx = blockIdx.x * blockDim.x + threadIdx.x;
    if (idx >= NT16 * NKS * 64 * 8) return;
    int j    = idx & 7;
    int lane = (idx >> 3) & 63;
    int ks   = (idx >> 9) & 15;
    int v16  = idx >> 13;
    int row  = v16 * 16 + (lane & 15);
    int k    = ks * 32 + 8 * (lane >> 4) + j;
    u16 h, l;
    split2(W[(size_t)row * DIM + k], h, l);
    size_t base = (size_t)((v16 * NKS + ks) * 2) * 512 + lane * 8 + j;
    Wpk[base]       = h;
    Wpk[base + 512] = l;
}

// -------- fast path: fused x-split staging (no pre-pass), TMF=64 -----------
// R12 post-mortem: pipeline depth was null -> main-loop structure keeps. The
// eliminable cost is the split_x pre-pass (98MB read + 98MB write ~= 31us).
// Fuse: wave ty stages tile ty via reg-staging (T14): issue 2 float4 x-loads
// for ks+2 at iteration top (full iteration of flight), split+ds_write after
// the MFMAs, lgkmcnt(0)+raw s_barrier (+sched_barrier, rule 18). Values are
// bit-identical to the xpk path (same split2, same fragment map). Bonus:
// A-bytes loaded halve (lo plane computed, not fetched).
__global__ __launch_bounds__(BLOCK, 2)
void vq_mfma_fused_kernel(const float* __restrict__ x,
                          const float* __restrict__ W,
                          const u16* __restrict__ Wpk,
                          const float* __restrict__ bias,
                          const float* __restrict__ codebook,
                          float* __restrict__ out,
                          float* __restrict__ avg_out) {
    __shared__ u16 As[3][4][2][512];     // 3 bufs x 4 rt x (hi,lo) x 1KB = 24KB
    __shared__ float avg_s[NUM_VARS];
    __shared__ float tv_s[TMF][4][2];
    __shared__ int   ti_s[TMF][4][2];
    __shared__ float m_s[TMF], gap_s[TMF], sum_s[TMF];
    __shared__ int   i1_s[TMF], i2_s[TMF], kb_s[TMF];

    const int tid  = threadIdx.x;
    const int lane = tid & 63;
    const int ty   = tid >> 6;
    const int l15  = lane & 15;
    const int l4   = lane >> 4;
    const int g    = blockIdx.x & 1;
    const int n0   = (blockIdx.x >> 1) * TMF;

    for (int i = tid; i < NUM_VARS; i += BLOCK) avg_s[i] = 0.f;

    const f32x4 zf = {0.f, 0.f, 0.f, 0.f};
    f32x4 acc[4][5];
#pragma unroll
    for (int rt = 0; rt < 4; ++rt)
#pragma unroll
        for (int ct = 0; ct < 5; ++ct) acc[rt][ct] = zf;

    // wave ty stages token-tile (n0/16 + ty); all waves consume all rt
    const float* xsrc = x + (size_t)(n0 + ty * 16 + l15) * DIM + 8 * l4;
    const u16* wpk_b = Wpk + (size_t)(g * 20 + ty * 5) * TSTRIDE + lane * 8;

    // prologue: stage ks=0,1 serially into buf 0,1
#pragma unroll
    for (int s = 0; s < 2; ++s) {
        float4 a = *(const float4*)(xsrc + s * 32);
        float4 b = *(const float4*)(xsrc + s * 32 + 4);
        u16x8 hv, lv;
        split8(a, b, hv, lv);
        *(u16x8*)&As[s][ty][0][lane * 8] = hv;
        *(u16x8*)&As[s][ty][1][lane * 8] = lv;
    }
    __syncthreads();

#pragma unroll 1
    for (int ks = 0; ks < NKS; ++ks) {
        const int cur = ks % 3;
        // B fragments (L2-resident Wpk) — issued first (oldest in VMEM queue)
        bf16x8 bh[5], bl[5];
#pragma unroll
        for (int ct = 0; ct < 5; ++ct) {
            const u16* wp = wpk_b + (size_t)(ct * NKS + ks) * 1024;
            bh[ct] = *(const bf16x8*)wp;
            bl[ct] = *(const bf16x8*)(wp + 512);
        }
        // stage loads for ks+2 (newest — not forced by B waits)
        float4 sx0, sx1;
        const int kst = ks + 2;
        if (kst < NKS) {
            sx0 = *(const float4*)(xsrc + (size_t)kst * 32);
            sx1 = *(const float4*)(xsrc + (size_t)kst * 32 + 4);
        }
        // A from LDS, 15 MFMAs per rt
#pragma unroll
        for (int rt = 0; rt < 4; ++rt) {
            bf16x8 ah = *(const bf16x8*)&As[cur][rt][0][lane * 8];
            bf16x8 al = *(const bf16x8*)&As[cur][rt][1][lane * 8];
#pragma unroll
            for (int ct = 0; ct < 5; ++ct) {
                acc[rt][ct] = __builtin_amdgcn_mfma_f32_16x16x32_bf16(ah, bh[ct], acc[rt][ct], 0, 0, 0);
                acc[rt][ct] = __builtin_amdgcn_mfma_f32_16x16x32_bf16(ah, bl[ct], acc[rt][ct], 0, 0, 0);
                acc[rt][ct] = __builtin_amdgcn_mfma_f32_16x16x32_bf16(al, bh[ct], acc[rt][ct], 0, 0, 0);
            }
        }
        // split + write buf (ks+2)%3 (read at iter ks-1; barrier-safe)
        if (kst < NKS) {
            const int nb = kst % 3;
            u16x8 hv, lv;
            split8(sx0, sx1, hv, lv);
            *(u16x8*)&As[nb][ty][0][lane * 8] = hv;
            *(u16x8*)&As[nb][ty][1][lane * 8] = lv;
        }
        asm volatile("s_waitcnt lgkmcnt(0)" ::: "memory");
        __builtin_amdgcn_sched_barrier(0);
        __builtin_amdgcn_s_barrier();
    }

    // bias (zeros in harness; kept for generality)
#pragma unroll
    for (int ct = 0; ct < 5; ++ct) {
        float bv = bias[g * NUM_VARS + ty * 80 + ct * 16 + l15];
#pragma unroll
        for (int rt = 0; rt < 4; ++rt)
#pragma unroll
            for (int j = 0; j < 4; ++j) acc[rt][ct][j] += bv;
    }

    // per-token wave-local top-2 (16-lane butterfly)
#pragma unroll
    for (int rt = 0; rt < 4; ++rt)
#pragma unroll
    for (int j = 0; j < 4; ++j) {
        float v1 = -3.4e38f, v2 = -3.4e38f;
        int   i1 = 0x7fffffff, i2 = 0x7fffffff;
#pragma unroll
        for (int ct = 0; ct < 5; ++ct) {
            float val = acc[rt][ct][j];
            int   vi  = ty * 80 + ct * 16 + l15;
            if ((val > v1) || (val == v1 && vi < i1)) { v2 = v1; i2 = i1; v1 = val; i1 = vi; }
            else if ((val > v2) || (val == v2 && vi < i2)) { v2 = val; i2 = vi; }
        }
#pragma unroll
        for (int off = 1; off <= 8; off <<= 1) {
            float o1 = __shfl_xor(v1, off); int oi1 = __shfl_xor(i1, off);
            float o2 = __shfl_xor(v2, off); int oi2 = __shfl_xor(i2, off);
            if ((o1 > v1) || (o1 == v1 && oi1 < i1)) { v2 = v1; i2 = i1; v1 = o1; i1 = oi1; }
            else if ((o1 > v2) || (o1 == v2 && oi1 < i2)) { v2 = o1; i2 = oi1; }
            if ((o2 > v1) || (o2 == v1 && oi2 < i1)) { v2 = v1; i2 = i1; v1 = o2; i1 = oi2; }
            else if ((o2 > v2) || (o2 == v2 && oi2 < i2)) { v2 = o2; i2 = oi2; }
        }
        if (l15 == 0) {
            const int T = rt * 16 + l4 * 4 + j;
            tv_s[T][ty][0] = v1; tv_s[T][ty][1] = v2;
            ti_s[T][ty][0] = i1; ti_s[T][ty][1] = i2;
        }
    }
    __syncthreads();

    // cross-wave merge (one thread per token)
    if (tid < TMF) {
        float v1 = -3.4e38f, v2 = -3.4e38f;
        int   i1 = 0x7fffffff, i2 = 0x7fffffff;
#pragma unroll
        for (int w = 0; w < 4; ++w)
#pragma unroll
            for (int q = 0; q < 2; ++q) {
                float val = tv_s[tid][w][q]; int vi = ti_s[tid][w][q];
                if ((val > v1) || (val == v1 && vi < i1)) { v2 = v1; i2 = i1; v1 = val; i1 = vi; }
                else if ((val > v2) || (val == v2 && vi < i2)) { v2 = val; i2 = vi; }
            }
        m_s[tid] = v1; gap_s[tid] = v1 - v2;
        i1_s[tid] = i1; i2_s[tid] = i2; kb_s[tid] = i1; sum_s[tid] = 0.f;
    }
    __syncthreads();

    // softmax: exp + per-token sum
#pragma unroll
    for (int rt = 0; rt < 4; ++rt)
#pragma unroll
    for (int j = 0; j < 4; ++j) {
        const int T = rt * 16 + l4 * 4 + j;
        const float m = m_s[T];
        float s = 0.f;
#pragma unroll
        for (int ct = 0; ct < 5; ++ct) {
            float e = __expf(acc[rt][ct][j] - m);
            acc[rt][ct][j] = e;
            s += e;
        }
#pragma unroll
        for (int off = 1; off <= 8; off <<= 1) s += __shfl_xor(s, off);
        if (l15 == 0) atomicAdd(&sum_s[T], s);
    }
    __syncthreads();

    // avg_probs partials: hoisted reciprocal, l4-shuffle reduce,
    // per-wave-exclusive plain adds
#pragma unroll
    for (int ct = 0; ct < 5; ++ct) {
        float tot = 0.f;
#pragma unroll
        for (int rt = 0; rt < 4; ++rt)
#pragma unroll
        for (int j = 0; j < 4; ++j) {
            const int T = rt * 16 + l4 * 4 + j;
            float v = acc[rt][ct][j] * (1.f / sum_s[T]);
            v += __shfl_xor(v, 16);
            v += __shfl_xor(v, 32);
            tot += v;
        }
        if (l4 == 0) avg_s[ty * 80 + ct * 16 + l15] += tot;
    }

    // f64 re-verify close argmaxes (bf16x3 logit err ~3e-4 << 0.05 gap)
    for (int t16 = 0; t16 < 16; ++t16) {
        const int T = ty * 16 + t16;
        if (gap_s[T] <= 0.05f) {
            const int i1 = i1_s[T], i2 = i2_s[T];
            const float* xr = x + (size_t)(n0 + T) * DIM;
            const float* w1 = W + (size_t)(g * NUM_VARS + i1) * DIM;
            const float* w2 = W + (size_t)(g * NUM_VARS + i2) * DIM;
            double d1 = 0.0, d2 = 0.0;
            for (int k = lane; k < DIM; k += 64) {
                double xv = (double)xr[k];
                d1 += xv * (double)w1[k];
                d2 += xv * (double)w2[k];
            }
#pragma unroll
            for (int off = 1; off <= 32; off <<= 1) {
                d1 += __shfl_xor(d1, off);
                d2 += __shfl_xor(d2, off);
            }
            d1 += (double)bias[g * NUM_VARS + i1];
            d2 += (double)bias[g * NUM_VARS + i2];
            if (lane == 0)
                kb_s[T] = (d2 > d1 || (d2 == d1 && i2 < i1)) ? i2 : i1;
        }
    }
    __syncthreads();

    // codebook gather -> out (coalesced float4): 64 tokens x 32 float4
#pragma unroll
    for (int i = 0; i < 8; ++i) {
        const int f = tid + i * BLOCK;
        const int T = f >> 5, p = f & 31;
        const int kb = kb_s[T];
        float4 cv = *(const float4*)(codebook +
                     (size_t)(g * NUM_VARS + kb) * VAR_DIM + p * 4);
        *(float4*)(out + (size_t)(n0 + T) * (GROUPS * VAR_DIM) + g * VAR_DIM + p * 4) = cv;
    }

    const float scale = 1.f / (float)NTOK;
    for (int i = tid; i < NUM_VARS; i += BLOCK)
        atomicAdd(&avg_out[g * NUM_VARS + i], avg_s[i] * scale);
}

// ---------------- fallback path (R6, proven): LDS-staged x ----------------
template <bool USE_WQ>
__global__ __launch_bounds__(BLOCK, 2)
void vq_mfma_kernel(const float* __restrict__ x,
                    const float* __restrict__ W,
                    const u16* __restrict__ Wpk,
                    const float* __restrict__ bias,
                    const float* __restrict__ codebook,
                    float* __restrict__ out,
                    float* __restrict__ avg_out) {
    __shared__ u16 xs_hi[TM][XP];
    __shared__ u16 xs_lo[TM][XP];
    __shared__ float avg_s[NUM_VARS];
    __shared__ float tv_s[TM][4][2];
    __shared__ int   ti_s[TM][4][2];
    __shared__ float m_s[TM], gap_s[TM], sum_s[TM];
    __shared__ int   i1_s[TM], i2_s[TM], kb_s[TM];

    const int tid  = threadIdx.x;
    const int lane = tid & 63;
    const int ty   = tid >> 6;
    const int l15  = lane & 15;
    const int l4   = lane >> 4;
    const int g    = blockIdx.x & 1;
    const int n0   = (blockIdx.x >> 1) * TM;

    for (int i = tid; i < NUM_VARS; i += BLOCK) avg_s[i] = 0.f;

    const f32x4 zf = {0.f, 0.f, 0.f, 0.f};
    f32x4 acc[2][5];
#pragma unroll
    for (int rt = 0; rt < 2; ++rt)
#pragma unroll
        for (int ct = 0; ct < 5; ++ct) acc[rt][ct] = zf;

    const int vw = g * NUM_VARS + ty * 80;

    for (int c = 0; c < DIM / KCH; ++c) {
        __syncthreads();
        {
            const int t  = tid >> 3;
            const int kb = (tid & 7) * 4;
            const float* xp = x + (size_t)(n0 + t) * DIM + c * KCH;
#pragma unroll
            for (int i = 0; i < 8; ++i) {
                const int k = kb + i * 32;
                float4 v = *(const float4*)(xp + k);
                u16x4 hv, lv; u16 h, l;
                split2(v.x, h, l); hv[0] = h; lv[0] = l;
                split2(v.y, h, l); hv[1] = h; lv[1] = l;
                split2(v.z, h, l); hv[2] = h; lv[2] = l;
                split2(v.w, h, l); hv[3] = h; lv[3] = l;
                *(u16x4*)&xs_hi[t][k] = hv;
                *(u16x4*)&xs_lo[t][k] = lv;
            }
        }
        __syncthreads();
#pragma unroll
        for (int ks = 0; ks < KCH / 32; ++ks) {
            const int ko = ks * 32 + 8 * l4;
            bf16x8 ah0 = *(const bf16x8*)&xs_hi[l15][ko];
            bf16x8 al0 = *(const bf16x8*)&xs_lo[l15][ko];
            bf16x8 ah1 = *(const bf16x8*)&xs_hi[16 + l15][ko];
            bf16x8 al1 = *(const bf16x8*)&xs_lo[16 + l15][ko];
            const int ksg = c * (KCH / 32) + ks;
#pragma unroll
            for (int ct = 0; ct < 5; ++ct) {
                bf16x8 bh, bl;
                if (USE_WQ) {
                    const int v16g = g * (NUM_VARS / 16) + ty * 5 + ct;
                    const u16* wp = Wpk + (size_t)((v16g * NKS + ksg) * 2) * 512 + lane * 8;
                    bh = *(const bf16x8*)wp;
                    bl = *(const bf16x8*)(wp + 512);
                } else {
                    const int kg = ksg * 32 + 8 * l4;
                    const float* wp = W + (size_t)(vw + ct * 16 + l15) * DIM + kg;
                    float4 wa = *(const float4*)wp;
                    float4 wb = *(const float4*)(wp + 4);
                    u16 h, l;
                    split2(wa.x, h, l); bh[0] = (short)h; bl[0] = (short)l;
                    split2(wa.y, h, l); bh[1] = (short)h; bl[1] = (short)l;
                    split2(wa.z, h, l); bh[2] = (short)h; bl[2] = (short)l;
                    split2(wa.w, h, l); bh[3] = (short)h; bl[3] = (short)l;
                    split2(wb.x, h, l); bh[4] = (short)h; bl[4] = (short)l;
                    split2(wb.y, h, l); bh[5] = (short)h; bl[5] = (short)l;
                    split2(wb.z, h, l); bh[6] = (short)h; bl[6] = (short)l;
                    split2(wb.w, h, l); bh[7] = (short)h; bl[7] = (short)l;
                }
                acc[0][ct] = __builtin_amdgcn_mfma_f32_16x16x32_bf16(ah0, bh, acc[0][ct], 0, 0, 0);
                acc[0][ct] = __builtin_amdgcn_mfma_f32_16x16x32_bf16(ah0, bl, acc[0][ct], 0, 0, 0);
                acc[0][ct] = __builtin_amdgcn_mfma_f32_16x16x32_bf16(al0, bh, acc[0][ct], 0, 0, 0);
                acc[1][ct] = __builtin_amdgcn_mfma_f32_16x16x32_bf16(ah1, bh, acc[1][ct], 0, 0, 0);
                acc[1][ct] = __builtin_amdgcn_mfma_f32_16x16x32_bf16(ah1, bl, acc[1][ct], 0, 0, 0);
                acc[1][ct] = __builtin_amdgcn_mfma_f32_16x16x32_bf16(al1, bh, acc[1][ct], 0, 0, 0);
            }
        }
    }

#pragma unroll
    for (int ct = 0; ct < 5; ++ct) {
        float bv = bias[vw + ct * 16 + l15];
#pragma unroll
        for (int rt = 0; rt < 2; ++rt)
#pragma unroll
            for (int j = 0; j < 4; ++j) acc[rt][ct][j] += bv;
    }

#pragma unroll
    for (int rt = 0; rt < 2; ++rt)
#pragma unroll
    for (int j = 0; j < 4; ++j) {
        float v1 = -3.4e38f, v2 = -3.4e38f;
        int   i1 = 0x7fffffff, i2 = 0x7fffffff;
#pragma unroll
        for (int ct = 0; ct < 5; ++ct) {
            float val = acc[rt][ct][j];
            int   vi  = ty * 80 + ct * 16 + l15;
            if ((val > v1) || (val == v1 && vi < i1)) { v2 = v1; i2 = i1; v1 = val; i1 = vi; }
            else if ((val > v2) || (val == v2 && vi < i2)) { v2 = val; i2 = vi; }
        }
#pragma unroll
        for (int off = 1; off <= 8; off <<= 1) {
            float o1 = __shfl_xor(v1, off); int oi1 = __shfl_xor(i1, off);
            float o2 = __shfl_xor(v2, off); int oi2 = __shfl_xor(i2, off);
            if ((o1 > v1) || (o1 == v1 && oi1 < i1)) { v2 = v1; i2 = i1; v1 = o1; i1 = oi1; }
            else if ((o1 > v2) || (o1 == v2 && oi1 < i2)) { v2 = o1; i2 = oi1; }
            if ((o2 > v1) || (o2 == v1 && oi2 < i1)) { v2 = v1; i2 = i1; v1 = o2; i1 = oi2; }
            else if ((o2 > v2) || (o2 == v2 && oi2 < i2)) { v2 = o2; i2 = oi2; }
        }
        if (l15 == 0) {
            const int T = rt * 16 + l4 * 4 + j;
            tv_s[T][ty][0] = v1; tv_s[T][ty][1] = v2;
            ti_s[T][ty][0] = i1; ti_s[T][ty][1] = i2;
        }
    }
    __syncthreads();

    if (tid < TM) {
        float v1 = -3.4e38f, v2 = -3.4e38f;
        int   i1 = 0x7fffffff, i2 = 0x7fffffff;
#pragma unroll
        for (int w = 0; w < 4; ++w)
#pragma unroll
            for (int q = 0; q < 2; ++q) {
                float val = tv_s[tid][w][q]; int vi = ti_s[tid][w][q];
                if ((val > v1) || (val == v1 && vi < i1)) { v2 = v1; i2 = i1; v1 = val; i1 = vi; }
                else if ((val > v2) || (val == v2 && vi < i2)) { v2 = val; i2 = vi; }
            }
        m_s[tid] = v1; gap_s[tid] = v1 - v2;
        i1_s[tid] = i1; i2_s[tid] = i2; kb_s[tid] = i1; sum_s[tid] = 0.f;
    }
    __syncthreads();

#pragma unroll
    for (int rt = 0; rt < 2; ++rt)
#pragma unroll
    for (int j = 0; j < 4; ++j) {
        const int T = rt * 16 + l4 * 4 + j;
        const float m = m_s[T];
        float s = 0.f;
#pragma unroll
        for (int ct = 0; ct < 5; ++ct) {
            float e = expf(acc[rt][ct][j] - m);
            acc[rt][ct][j] = e;
            s += e;
        }
#pragma unroll
        for (int off = 1; off <= 8; off <<= 1) s += __shfl_xor(s, off);
        if (l15 == 0) atomicAdd(&sum_s[T], s);
    }
    __syncthreads();

#pragma unroll
    for (int ct = 0; ct < 5; ++ct) {
        float tot = 0.f;
#pragma unroll
        for (int rt = 0; rt < 2; ++rt)
#pragma unroll
        for (int j = 0; j < 4; ++j) {
            const int T = rt * 16 + l4 * 4 + j;
            float v = acc[rt][ct][j] / sum_s[T];
            v += __shfl_xor(v, 16);
            v += __shfl_xor(v, 32);
            tot += v;
        }
        if (l4 == 0) avg_s[ty * 80 + ct * 16 + l15] += tot;
    }

    for (int t8 = 0; t8 < 8; ++t8) {
        const int T = ty * 8 + t8;
        if (gap_s[T] <= 0.05f) {
            const int i1 = i1_s[T], i2 = i2_s[T];
            const float* xr = x + (size_t)(n0 + T) * DIM;
            const float* w1 = W + (size_t)(g * NUM_VARS + i1) * DIM;
            const float* w2 = W + (size_t)(g * NUM_VARS + i2) * DIM;
            double d1 = 0.0, d2 = 0.0;
            for (int k = lane; k < DIM; k += 64) {
                double xv = (double)xr[k];
                d1 += xv * (double)w1[k];
                d2 += xv * (double)w2[k];
            }
#pragma unroll
            for (int off = 1; off <= 32; off <<= 1) {
                d1 += __shfl_xor(d1, off);
                d2 += __shfl_xor(d2, off);
            }
            d1 += (double)bias[g * NUM_VARS + i1];
            d2 += (double)bias[g * NUM_VARS + i2];
            if (lane == 0)
                kb_s[T] = (d2 > d1 || (d2 == d1 && i2 < i1)) ? i2 : i1;
        }
    }
    __syncthreads();

#pragma unroll
    for (int i = 0; i < 4; ++i) {
        const int f = tid + i * BLOCK;
        const int T = f >> 5, p = f & 31;
        const int kb = kb_s[T];
        float4 cv = *(const float4*)(codebook +
                     (size_t)(g * NUM_VARS + kb) * VAR_DIM + p * 4);
        *(float4*)(out + (size_t)(n0 + T) * (GROUPS * VAR_DIM) + g * VAR_DIM + p * 4) = cv;
    }

    const float scale = 1.f / (float)NTOK;
    for (int i = tid; i < NUM_VARS; i += BLOCK)
        atomicAdd(&avg_out[g * NUM_VARS + i], avg_s[i] * scale);
}

extern "C" void kernel_launch(void* const* d_in, const int* in_sizes, int n_in,
                              void* d_out, int out_size, void* d_ws, size_t ws_size,
                              hipStream_t stream) {
    const float* x  = (const float*)d_in[0];
    const float* W  = (const float*)d_in[1];
    const float* b  = (const float*)d_in[2];
    const float* cb = (const float*)d_in[3];
    float* out = (float*)d_out;
    float* avg = out + (size_t)NTOK * GROUPS * VAR_DIM;

    hipMemsetAsync(avg, 0, NVT * sizeof(float), stream);

    const size_t wpk_bytes = (size_t)NT16 * NKS * 2 * 512 * sizeof(u16);   // 1.31 MB

    if (ws_size >= wpk_bytes) {
        u16* Wpk = (u16*)d_ws;
        pack_w_kernel<<<(NT16 * NKS * 64 * 8 + 255) / 256, 256, 0, stream>>>(W, Wpk);
        vq_mfma_fused_kernel<<<(NTOK / TMF) * GROUPS, BLOCK, 0, stream>>>(
            x, W, Wpk, b, cb, out, avg);
    } else {
        vq_mfma_kernel<false><<<(NTOK / TM) * GROUPS, BLOCK, 0, stream>>>(x, W, nullptr, b, cb, out, avg);
    }
}

// Round 15
// 162.743 us; speedup vs baseline: 1.1598x; 1.0111x over previous
//
#include <hip/hip_runtime.h>

#define GROUPS 2
#define NUM_VARS 320
#define NVT 640
#define DIM 512
#define VAR_DIM 128
#define NTOK 48000
#define TM 32            // (fallback path) tokens per block
#define TMF 64           // fast-path tokens per block (4 row-tiles)
#define BLOCK 256
#define KCH 256          // (fallback path) K-chunk staged in LDS
#define XP 264           // (fallback path) padded row stride (ushorts)
#define NT16 40          // total 16-var tiles (NVT/16)
#define NKS 16           // total 32-k slices (DIM/32)
#define TSTRIDE (NKS * 2 * 512)   // u16 elements per packed W 16-row tile

typedef short bf16x8 __attribute__((ext_vector_type(8)));
typedef float f32x4  __attribute__((ext_vector_type(4)));
typedef unsigned short u16;
typedef u16 u16x4 __attribute__((ext_vector_type(4)));
typedef u16 u16x8 __attribute__((ext_vector_type(8)));

__device__ inline u16 bf16_rne(float f) {
    unsigned u = __builtin_bit_cast(unsigned, f);
    return (u16)((u + 0x7fffu + ((u >> 16) & 1u)) >> 16);
}
__device__ inline void split2(float f, u16& h, u16& l) {
    h = bf16_rne(f);
    float fh = __builtin_bit_cast(float, (unsigned)h << 16);
    l = bf16_rne(f - fh);
}
__device__ inline void split8(float4 a, float4 b, u16x8& hv, u16x8& lv) {
    u16 h, l;
    split2(a.x, h, l); hv[0] = h; lv[0] = l;
    split2(a.y, h, l); hv[1] = h; lv[1] = l;
    split2(a.z, h, l); hv[2] = h; lv[2] = l;
    split2(a.w, h, l); hv[3] = h; lv[3] = l;
    split2(b.x, h, l); hv[4] = h; lv[4] = l;
    split2(b.y, h, l); hv[5] = h; lv[5] = l;
    split2(b.z, h, l); hv[6] = h; lv[6] = l;
    split2(b.w, h, l); hv[7] = h; lv[7] = l;
}

// Pre-split W into bf16 hi/lo in MFMA-fragment order (validated R5-R13, absmax=0):
//   offset = ((v16*NKS+ks)*2+hilo)*512 + lane*8 + j
//   row = v16*16 + (lane&15), k = ks*32 + 8*(lane>>4) + j.
// NOTE (R14 lesson): bf16x2 (dropping the A*(W-Whi) term) FAILS — logit err
// std ~0.026 lets the true argmax fall outside the computed top-2, which the
// f64 top-2 re-verify cannot catch. bf16x3's err ~3e-4 keeps "true winner
// outside top-2" probability negligible. Do not drop the Blo plane.
__global__ void pack_w_kernel(const float* __restrict__ W, u16* __restrict__ Wpk) {
    int idx = blockIdx.x * blockDim.x + threadIdx.x;
    if (idx >= NT16 * NKS * 64 * 8) return;
    int j    = idx & 7;
    int lane = (idx >> 3) & 63;
    int ks   = (idx >> 9) & 15;
    int v16  = idx >> 13;
    int row  = v16 * 16 + (lane & 15);
    int k    = ks * 32 + 8 * (lane >> 4) + j;
    u16 h, l;
    split2(W[(size_t)row * DIM + k], h, l);
    size_t base = (size_t)((v16 * NKS + ks) * 2) * 512 + lane * 8 + j;
    Wpk[base]       = h;
    Wpk[base + 512] = l;
}

// -------- fast path: fused x-split staging (no pre-pass), TMF=64, bf16x3 ----
// Proven R13 structure: wave ty reg-stages its token-tile (T14 issue-early /
// split+ds_write-late), 3-buffer rotation, lgkmcnt(0)+sched_barrier+s_barrier
// per ks. B (hi+lo) direct from L2-resident Wpk. acc = 80 f32; 76 VGPR ->
// 3 waves/SIMD.
__global__ __launch_bounds__(BLOCK, 2)
void vq_mfma_fused_kernel(const float* __restrict__ x,
                          const float* __restrict__ W,
                          const u16* __restrict__ Wpk,
                          const float* __restrict__ bias,
                          const float* __restrict__ codebook,
                          float* __restrict__ out,
                          float* __restrict__ avg_out) {
    __shared__ u16 As[3][4][2][512];     // 3 bufs x 4 rt x (hi,lo) x 1KB = 24KB
    __shared__ float avg_s[NUM_VARS];
    __shared__ float tv_s[TMF][4][2];
    __shared__ int   ti_s[TMF][4][2];
    __shared__ float m_s[TMF], gap_s[TMF], sum_s[TMF];
    __shared__ int   i1_s[TMF], i2_s[TMF], kb_s[TMF];

    const int tid  = threadIdx.x;
    const int lane = tid & 63;
    const int ty   = tid >> 6;
    const int l15  = lane & 15;
    const int l4   = lane >> 4;
    const int g    = blockIdx.x & 1;
    const int n0   = (blockIdx.x >> 1) * TMF;

    for (int i = tid; i < NUM_VARS; i += BLOCK) avg_s[i] = 0.f;

    const f32x4 zf = {0.f, 0.f, 0.f, 0.f};
    f32x4 acc[4][5];
#pragma unroll
    for (int rt = 0; rt < 4; ++rt)
#pragma unroll
        for (int ct = 0; ct < 5; ++ct) acc[rt][ct] = zf;

    // wave ty stages token-tile (n0/16 + ty); all waves consume all rt
    const float* xsrc = x + (size_t)(n0 + ty * 16 + l15) * DIM + 8 * l4;
    const u16* wpk_b = Wpk + (size_t)(g * 20 + ty * 5) * TSTRIDE + lane * 8;

    // prologue: stage ks=0,1 serially into buf 0,1
#pragma unroll
    for (int s = 0; s < 2; ++s) {
        float4 a = *(const float4*)(xsrc + s * 32);
        float4 b = *(const float4*)(xsrc + s * 32 + 4);
        u16x8 hv, lv;
        split8(a, b, hv, lv);
        *(u16x8*)&As[s][ty][0][lane * 8] = hv;
        *(u16x8*)&As[s][ty][1][lane * 8] = lv;
    }
    __syncthreads();

#pragma unroll 1
    for (int ks = 0; ks < NKS; ++ks) {
        const int cur = ks % 3;
        // B fragments (L2-resident Wpk) — issued first (oldest in VMEM queue)
        bf16x8 bh[5], bl[5];
#pragma unroll
        for (int ct = 0; ct < 5; ++ct) {
            const u16* wp = wpk_b + (size_t)(ct * NKS + ks) * 1024;
            bh[ct] = *(const bf16x8*)wp;
            bl[ct] = *(const bf16x8*)(wp + 512);
        }
        // stage loads for ks+2 (newest — not forced by B waits)
        float4 sx0, sx1;
        const int kst = ks + 2;
        if (kst < NKS) {
            sx0 = *(const float4*)(xsrc + (size_t)kst * 32);
            sx1 = *(const float4*)(xsrc + (size_t)kst * 32 + 4);
        }
        // A from LDS, 15 MFMAs per rt
#pragma unroll
        for (int rt = 0; rt < 4; ++rt) {
            bf16x8 ah = *(const bf16x8*)&As[cur][rt][0][lane * 8];
            bf16x8 al = *(const bf16x8*)&As[cur][rt][1][lane * 8];
#pragma unroll
            for (int ct = 0; ct < 5; ++ct) {
                acc[rt][ct] = __builtin_amdgcn_mfma_f32_16x16x32_bf16(ah, bh[ct], acc[rt][ct], 0, 0, 0);
                acc[rt][ct] = __builtin_amdgcn_mfma_f32_16x16x32_bf16(ah, bl[ct], acc[rt][ct], 0, 0, 0);
                acc[rt][ct] = __builtin_amdgcn_mfma_f32_16x16x32_bf16(al, bh[ct], acc[rt][ct], 0, 0, 0);
            }
        }
        // split + write buf (ks+2)%3 (read at iter ks-1; barrier-safe)
        if (kst < NKS) {
            const int nb = kst % 3;
            u16x8 hv, lv;
            split8(sx0, sx1, hv, lv);
            *(u16x8*)&As[nb][ty][0][lane * 8] = hv;
            *(u16x8*)&As[nb][ty][1][lane * 8] = lv;
        }
        asm volatile("s_waitcnt lgkmcnt(0)" ::: "memory");
        __builtin_amdgcn_sched_barrier(0);
        __builtin_amdgcn_s_barrier();
    }

    // bias (zeros in harness; kept for generality)
#pragma unroll
    for (int ct = 0; ct < 5; ++ct) {
        float bv = bias[g * NUM_VARS + ty * 80 + ct * 16 + l15];
#pragma unroll
        for (int rt = 0; rt < 4; ++rt)
#pragma unroll
            for (int j = 0; j < 4; ++j) acc[rt][ct][j] += bv;
    }

    // per-token wave-local top-2 (16-lane butterfly)
#pragma unroll
    for (int rt = 0; rt < 4; ++rt)
#pragma unroll
    for (int j = 0; j < 4; ++j) {
        float v1 = -3.4e38f, v2 = -3.4e38f;
        int   i1 = 0x7fffffff, i2 = 0x7fffffff;
#pragma unroll
        for (int ct = 0; ct < 5; ++ct) {
            float val = acc[rt][ct][j];
            int   vi  = ty * 80 + ct * 16 + l15;
            if ((val > v1) || (val == v1 && vi < i1)) { v2 = v1; i2 = i1; v1 = val; i1 = vi; }
            else if ((val > v2) || (val == v2 && vi < i2)) { v2 = val; i2 = vi; }
        }
#pragma unroll
        for (int off = 1; off <= 8; off <<= 1) {
            float o1 = __shfl_xor(v1, off); int oi1 = __shfl_xor(i1, off);
            float o2 = __shfl_xor(v2, off); int oi2 = __shfl_xor(i2, off);
            if ((o1 > v1) || (o1 == v1 && oi1 < i1)) { v2 = v1; i2 = i1; v1 = o1; i1 = oi1; }
            else if ((o1 > v2) || (o1 == v2 && oi1 < i2)) { v2 = o1; i2 = oi1; }
            if ((o2 > v1) || (o2 == v1 && oi2 < i1)) { v2 = v1; i2 = i1; v1 = o2; i1 = oi2; }
            else if ((o2 > v2) || (o2 == v2 && oi2 < i2)) { v2 = o2; i2 = oi2; }
        }
        if (l15 == 0) {
            const int T = rt * 16 + l4 * 4 + j;
            tv_s[T][ty][0] = v1; tv_s[T][ty][1] = v2;
            ti_s[T][ty][0] = i1; ti_s[T][ty][1] = i2;
        }
    }
    __syncthreads();

    // cross-wave merge (one thread per token)
    if (tid < TMF) {
        float v1 = -3.4e38f, v2 = -3.4e38f;
        int   i1 = 0x7fffffff, i2 = 0x7fffffff;
#pragma unroll
        for (int w = 0; w < 4; ++w)
#pragma unroll
            for (int q = 0; q < 2; ++q) {
                float val = tv_s[tid][w][q]; int vi = ti_s[tid][w][q];
                if ((val > v1) || (val == v1 && vi < i1)) { v2 = v1; i2 = i1; v1 = val; i1 = vi; }
                else if ((val > v2) || (val == v2 && vi < i2)) { v2 = val; i2 = vi; }
            }
        m_s[tid] = v1; gap_s[tid] = v1 - v2;
        i1_s[tid] = i1; i2_s[tid] = i2; kb_s[tid] = i1; sum_s[tid] = 0.f;
    }
    __syncthreads();

    // softmax: exp + per-token sum
#pragma unroll
    for (int rt = 0; rt < 4; ++rt)
#pragma unroll
    for (int j = 0; j < 4; ++j) {
        const int T = rt * 16 + l4 * 4 + j;
        const float m = m_s[T];
        float s = 0.f;
#pragma unroll
        for (int ct = 0; ct < 5; ++ct) {
            float e = __expf(acc[rt][ct][j] - m);
            acc[rt][ct][j] = e;
            s += e;
        }
#pragma unroll
        for (int off = 1; off <= 8; off <<= 1) s += __shfl_xor(s, off);
        if (l15 == 0) atomicAdd(&sum_s[T], s);
    }
    __syncthreads();

    // avg_probs partials: hoisted reciprocal, l4-shuffle reduce,
    // per-wave-exclusive plain adds
#pragma unroll
    for (int ct = 0; ct < 5; ++ct) {
        float tot = 0.f;
#pragma unroll
        for (int rt = 0; rt < 4; ++rt)
#pragma unroll
        for (int j = 0; j < 4; ++j) {
            const int T = rt * 16 + l4 * 4 + j;
            float v = acc[rt][ct][j] * (1.f / sum_s[T]);
            v += __shfl_xor(v, 16);
            v += __shfl_xor(v, 32);
            tot += v;
        }
        if (l4 == 0) avg_s[ty * 80 + ct * 16 + l15] += tot;
    }

    // f64 re-verify close argmaxes (bf16x3 logit err ~3e-4 << 0.05 gap)
    for (int t16 = 0; t16 < 16; ++t16) {
        const int T = ty * 16 + t16;
        if (gap_s[T] <= 0.05f) {
            const int i1 = i1_s[T], i2 = i2_s[T];
            const float* xr = x + (size_t)(n0 + T) * DIM;
            const float* w1 = W + (size_t)(g * NUM_VARS + i1) * DIM;
            const float* w2 = W + (size_t)(g * NUM_VARS + i2) * DIM;
            double d1 = 0.0, d2 = 0.0;
            for (int k = lane; k < DIM; k += 64) {
                double xv = (double)xr[k];
                d1 += xv * (double)w1[k];
                d2 += xv * (double)w2[k];
            }
#pragma unroll
            for (int off = 1; off <= 32; off <<= 1) {
                d1 += __shfl_xor(d1, off);
                d2 += __shfl_xor(d2, off);
            }
            d1 += (double)bias[g * NUM_VARS + i1];
            d2 += (double)bias[g * NUM_VARS + i2];
            if (lane == 0)
                kb_s[T] = (d2 > d1 || (d2 == d1 && i2 < i1)) ? i2 : i1;
        }
    }
    __syncthreads();

    // codebook gather -> out (coalesced float4): 64 tokens x 32 float4
#pragma unroll
    for (int i = 0; i < 8; ++i) {
        const int f = tid + i * BLOCK;
        const int T = f >> 5, p = f & 31;
        const int kb = kb_s[T];
        float4 cv = *(const float4*)(codebook +
                     (size_t)(g * NUM_VARS + kb) * VAR_DIM + p * 4);
        *(float4*)(out + (size_t)(n0 + T) * (GROUPS * VAR_DIM) + g * VAR_DIM + p * 4) = cv;
    }

    const float scale = 1.f / (float)NTOK;
    for (int i = tid; i < NUM_VARS; i += BLOCK)
        atomicAdd(&avg_out[g * NUM_VARS + i], avg_s[i] * scale);
}

// ---------------- fallback path (no workspace): in-loop W split ------------
__global__ __launch_bounds__(BLOCK, 2)
void vq_mfma_kernel(const float* __restrict__ x,
                    const float* __restrict__ W,
                    const float* __restrict__ bias,
                    const float* __restrict__ codebook,
                    float* __restrict__ out,
                    float* __restrict__ avg_out) {
    __shared__ u16 xs_hi[TM][XP];
    __shared__ u16 xs_lo[TM][XP];
    __shared__ float avg_s[NUM_VARS];
    __shared__ float tv_s[TM][4][2];
    __shared__ int   ti_s[TM][4][2];
    __shared__ float m_s[TM], gap_s[TM], sum_s[TM];
    __shared__ int   i1_s[TM], i2_s[TM], kb_s[TM];

    const int tid  = threadIdx.x;
    const int lane = tid & 63;
    const int ty   = tid >> 6;
    const int l15  = lane & 15;
    const int l4   = lane >> 4;
    const int g    = blockIdx.x & 1;
    const int n0   = (blockIdx.x >> 1) * TM;

    for (int i = tid; i < NUM_VARS; i += BLOCK) avg_s[i] = 0.f;

    const f32x4 zf = {0.f, 0.f, 0.f, 0.f};
    f32x4 acc[2][5];
#pragma unroll
    for (int rt = 0; rt < 2; ++rt)
#pragma unroll
        for (int ct = 0; ct < 5; ++ct) acc[rt][ct] = zf;

    const int vw = g * NUM_VARS + ty * 80;

    for (int c = 0; c < DIM / KCH; ++c) {
        __syncthreads();
        {
            const int t  = tid >> 3;
            const int kb = (tid & 7) * 4;
            const float* xp = x + (size_t)(n0 + t) * DIM + c * KCH;
#pragma unroll
            for (int i = 0; i < 8; ++i) {
                const int k = kb + i * 32;
                float4 v = *(const float4*)(xp + k);
                u16x4 hv, lv; u16 h, l;
                split2(v.x, h, l); hv[0] = h; lv[0] = l;
                split2(v.y, h, l); hv[1] = h; lv[1] = l;
                split2(v.z, h, l); hv[2] = h; lv[2] = l;
                split2(v.w, h, l); hv[3] = h; lv[3] = l;
                *(u16x4*)&xs_hi[t][k] = hv;
                *(u16x4*)&xs_lo[t][k] = lv;
            }
        }
        __syncthreads();
#pragma unroll
        for (int ks = 0; ks < KCH / 32; ++ks) {
            const int ko = ks * 32 + 8 * l4;
            bf16x8 ah0 = *(const bf16x8*)&xs_hi[l15][ko];
            bf16x8 al0 = *(const bf16x8*)&xs_lo[l15][ko];
            bf16x8 ah1 = *(const bf16x8*)&xs_hi[16 + l15][ko];
            bf16x8 al1 = *(const bf16x8*)&xs_lo[16 + l15][ko];
            const int kg = c * KCH + ks * 32 + 8 * l4;
#pragma unroll
            for (int ct = 0; ct < 5; ++ct) {
                const float* wp = W + (size_t)(vw + ct * 16 + l15) * DIM + kg;
                float4 wa = *(const float4*)wp;
                float4 wb = *(const float4*)(wp + 4);
                bf16x8 bh, bl; u16 h, l;
                split2(wa.x, h, l); bh[0] = (short)h; bl[0] = (short)l;
                split2(wa.y, h, l); bh[1] = (short)h; bl[1] = (short)l;
                split2(wa.z, h, l); bh[2] = (short)h; bl[2] = (short)l;
                split2(wa.w, h, l); bh[3] = (short)h; bl[3] = (short)l;
                split2(wb.x, h, l); bh[4] = (short)h; bl[4] = (short)l;
                split2(wb.y, h, l); bh[5] = (short)h; bl[5] = (short)l;
                split2(wb.z, h, l); bh[6] = (short)h; bl[6] = (short)l;
                split2(wb.w, h, l); bh[7] = (short)h; bl[7] = (short)l;
                acc[0][ct] = __builtin_amdgcn_mfma_f32_16x16x32_bf16(ah0, bh, acc[0][ct], 0, 0, 0);
                acc[0][ct] = __builtin_amdgcn_mfma_f32_16x16x32_bf16(ah0, bl, acc[0][ct], 0, 0, 0);
                acc[0][ct] = __builtin_amdgcn_mfma_f32_16x16x32_bf16(al0, bh, acc[0][ct], 0, 0, 0);
                acc[1][ct] = __builtin_amdgcn_mfma_f32_16x16x32_bf16(ah1, bh, acc[1][ct], 0, 0, 0);
                acc[1][ct] = __builtin_amdgcn_mfma_f32_16x16x32_bf16(ah1, bl, acc[1][ct], 0, 0, 0);
                acc[1][ct] = __builtin_amdgcn_mfma_f32_16x16x32_bf16(al1, bh, acc[1][ct], 0, 0, 0);
            }
        }
    }

#pragma unroll
    for (int ct = 0; ct < 5; ++ct) {
        float bv = bias[vw + ct * 16 + l15];
#pragma unroll
        for (int rt = 0; rt < 2; ++rt)
#pragma unroll
            for (int j = 0; j < 4; ++j) acc[rt][ct][j] += bv;
    }

#pragma unroll
    for (int rt = 0; rt < 2; ++rt)
#pragma unroll
    for (int j = 0; j < 4; ++j) {
        float v1 = -3.4e38f, v2 = -3.4e38f;
        int   i1 = 0x7fffffff, i2 = 0x7fffffff;
#pragma unroll
        for (int ct = 0; ct < 5; ++ct) {
            float val = acc[rt][ct][j];
            int   vi  = ty * 80 + ct * 16 + l15;
            if ((val > v1) || (val == v1 && vi < i1)) { v2 = v1; i2 = i1; v1 = val; i1 = vi; }
            else if ((val > v2) || (val == v2 && vi < i2)) { v2 = val; i2 = vi; }
        }
#pragma unroll
        for (int off = 1; off <= 8; off <<= 1) {
            float o1 = __shfl_xor(v1, off); int oi1 = __shfl_xor(i1, off);
            float o2 = __shfl_xor(v2, off); int oi2 = __shfl_xor(i2, off);
            if ((o1 > v1) || (o1 == v1 && oi1 < i1)) { v2 = v1; i2 = i1; v1 = o1; i1 = oi1; }
            else if ((o1 > v2) || (o1 == v2 && oi1 < i2)) { v2 = o1; i2 = oi1; }
            if ((o2 > v1) || (o2 == v1 && oi2 < i1)) { v2 = v1; i2 = i1; v1 = o2; i1 = oi2; }
            else if ((o2 > v2) || (o2 == v2 && oi2 < i2)) { v2 = o2; i2 = oi2; }
        }
        if (l15 == 0) {
            const int T = rt * 16 + l4 * 4 + j;
            tv_s[T][ty][0] = v1; tv_s[T][ty][1] = v2;
            ti_s[T][ty][0] = i1; ti_s[T][ty][1] = i2;
        }
    }
    __syncthreads();

    if (tid < TM) {
        float v1 = -3.4e38f, v2 = -3.4e38f;
        int   i1 = 0x7fffffff, i2 = 0x7fffffff;
#pragma unroll
        for (int w = 0; w < 4; ++w)
#pragma unroll
            for (int q = 0; q < 2; ++q) {
                float val = tv_s[tid][w][q]; int vi = ti_s[tid][w][q];
                if ((val > v1) || (val == v1 && vi < i1)) { v2 = v1; i2 = i1; v1 = val; i1 = vi; }
                else if ((val > v2) || (val == v2 && vi < i2)) { v2 = val; i2 = vi; }
            }
        m_s[tid] = v1; gap_s[tid] = v1 - v2;
        i1_s[tid] = i1; i2_s[tid] = i2; kb_s[tid] = i1; sum_s[tid] = 0.f;
    }
    __syncthreads();

#pragma unroll
    for (int rt = 0; rt < 2; ++rt)
#pragma unroll
    for (int j = 0; j < 4; ++j) {
        const int T = rt * 16 + l4 * 4 + j;
        const float m = m_s[T];
        float s = 0.f;
#pragma unroll
        for (int ct = 0; ct < 5; ++ct) {
            float e = expf(acc[rt][ct][j] - m);
            acc[rt][ct][j] = e;
            s += e;
        }
#pragma unroll
        for (int off = 1; off <= 8; off <<= 1) s += __shfl_xor(s, off);
        if (l15 == 0) atomicAdd(&sum_s[T], s);
    }
    __syncthreads();

#pragma unroll
    for (int ct = 0; ct < 5; ++ct) {
        float tot = 0.f;
#pragma unroll
        for (int rt = 0; rt < 2; ++rt)
#pragma unroll
        for (int j = 0; j < 4; ++j) {
            const int T = rt * 16 + l4 * 4 + j;
            float v = acc[rt][ct][j] / sum_s[T];
            v += __shfl_xor(v, 16);
            v += __shfl_xor(v, 32);
            tot += v;
        }
        if (l4 == 0) avg_s[ty * 80 + ct * 16 + l15] += tot;
    }

    for (int t8 = 0; t8 < 8; ++t8) {
        const int T = ty * 8 + t8;
        if (gap_s[T] <= 0.05f) {
            const int i1 = i1_s[T], i2 = i2_s[T];
            const float* xr = x + (size_t)(n0 + T) * DIM;
            const float* w1 = W + (size_t)(g * NUM_VARS + i1) * DIM;
            const float* w2 = W + (size_t)(g * NUM_VARS + i2) * DIM;
            double d1 = 0.0, d2 = 0.0;
            for (int k = lane; k < DIM; k += 64) {
                double xv = (double)xr[k];
                d1 += xv * (double)w1[k];
                d2 += xv * (double)w2[k];
            }
#pragma unroll
            for (int off = 1; off <= 32; off <<= 1) {
                d1 += __shfl_xor(d1, off);
                d2 += __shfl_xor(d2, off);
            }
            d1 += (double)bias[g * NUM_VARS + i1];
            d2 += (double)bias[g * NUM_VARS + i2];
            if (lane == 0)
                kb_s[T] = (d2 > d1 || (d2 == d1 && i2 < i1)) ? i2 : i1;
        }
    }
    __syncthreads();

#pragma unroll
    for (int i = 0; i < 4; ++i) {
        const int f = tid + i * BLOCK;
        const int T = f >> 5, p = f & 31;
        const int kb = kb_s[T];
        float4 cv = *(const float4*)(codebook +
                     (size_t)(g * NUM_VARS + kb) * VAR_DIM + p * 4);
        *(float4*)(out + (size_t)(n0 + T) * (GROUPS * VAR_DIM) + g * VAR_DIM + p * 4) = cv;
    }

    const float scale = 1.f / (float)NTOK;
    for (int i = tid; i < NUM_VARS; i += BLOCK)
        atomicAdd(&avg_out[g * NUM_VARS + i], avg_s[i] * scale);
}

extern "C" void kernel_launch(void* const* d_in, const int* in_sizes, int n_in,
                              void* d_out, int out_size, void* d_ws, size_t ws_size,
                              hipStream_t stream) {
    const float* x  = (const float*)d_in[0];
    const float* W  = (const float*)d_in[1];
    const float* b  = (const float*)d_in[2];
    const float* cb = (const float*)d_in[3];
    float* out = (float*)d_out;
    float* avg = out + (size_t)NTOK * GROUPS * VAR_DIM;

    hipMemsetAsync(avg, 0, NVT * sizeof(float), stream);

    const size_t wpk_bytes = (size_t)NT16 * NKS * 2 * 512 * sizeof(u16);   // 1.31 MB

    if (ws_size >= wpk_bytes) {
        u16* Wpk = (u16*)d_ws;
        pack_w_kernel<<<(NT16 * NKS * 64 * 8 + 255) / 256, 256, 0, stream>>>(W, Wpk);
        vq_mfma_fused_kernel<<<(NTOK / TMF) * GROUPS, BLOCK, 0, stream>>>(
            x, W, Wpk, b, cb, out, avg);
    } else {
        vq_mfma_kernel<<<(NTOK / TM) * GROUPS, BLOCK, 0, stream>>>(x, W, b, cb, out, avg);
    }
}